// Round 16
// baseline (152.563 us; speedup 1.0000x reference)
//
#include <hip/hip_runtime.h>
#include <math.h>

// Problem dims (fixed by setup_inputs)
#define BB 16
#define HH 64
#define WW 64
#define CC 512
#define CI 64
#define NROWS (BB * HH * WW)  // 65536 rows of length C
#define LN_EPS 1e-3f

typedef __attribute__((ext_vector_type(8))) short bf16x8;
typedef __attribute__((ext_vector_type(4))) float f32x4;

__device__ __forceinline__ unsigned short f2bf(float f) {
  union {
    float f;
    unsigned int u;
  } v;
  v.f = f;
  unsigned int r = v.u + 0x7FFF + ((v.u >> 16) & 1);  // RNE
  return (unsigned short)(r >> 16);
}

__device__ __forceinline__ float bf2f(unsigned short u) {
  union {
    unsigned int u;
    float f;
  } v;
  v.u = ((unsigned int)u) << 16;
  return v.f;
}

// Packed f32->bf16 (RNE) — register-only asm, deps tracked via operands.
__device__ __forceinline__ unsigned int cvt_pk_bf16(float a, float b) {
  unsigned int r;
  asm("v_cvt_pk_bf16_f32 %0, %1, %2" : "=v"(r) : "v"(a), "v"(b));
  return r;  // low16 = bf(a), high16 = bf(b)
}

// Async global->LDS, 16B per lane. LDS dest is wave-uniform base + lane*16;
// the GLOBAL source address is per-lane.
__device__ __forceinline__ void gload_lds16(const float* g, float* l) {
  __builtin_amdgcn_global_load_lds(
      (const __attribute__((address_space(1))) void*)g,
      (__attribute__((address_space(3))) void*)l, 16, 0, 0);
}

// ---------------------------------------------------------------------------
// Prep: transpose weights to k-contiguous bf16. WcT[col][k]: col<64 -> Wf,
// col in [64,128) -> Wh. WoT[col][k] from Wo[k][col].
// ---------------------------------------------------------------------------
__global__ __launch_bounds__(256) void sgsa_prep(
    const float* __restrict__ Wf, const float* __restrict__ Wh,
    const float* __restrict__ Wo, unsigned short* __restrict__ WcT,
    unsigned short* __restrict__ WoT) {
  int tid = blockIdx.x * 256 + threadIdx.x;
  for (int i = tid; i < 128 * 512; i += gridDim.x * 256) {
    int col = i >> 9, k = i & 511;
    float v = (col < 64) ? Wf[k * 64 + col] : Wh[k * 64 + (col - 64)];
    WcT[i] = f2bf(v);
  }
  for (int i = tid; i < 512 * 64; i += gridDim.x * 256) {
    int col = i >> 6, k = i & 63;
    WoT[i] = f2bf(Wo[k * 512 + col]);
  }
}

// ---------------------------------------------------------------------------
// K1 (double-buffered staged MFMA, 64-row blocks) — UNCHANGED from R11
// (~42 µs measured): [fg|hl] = LN(x @ [Wf|Wh]); BK=64 dbuf, issue-early
// staging, source-side XOR swizzle, 2 waves/block, grid 1024 (4 blocks/CU).
// ---------------------------------------------------------------------------
__global__ __launch_bounds__(128) void sgsa_k1_mfma(
    const float* __restrict__ x, const unsigned short* __restrict__ WcT,
    const float* __restrict__ gf, const float* __restrict__ bf,
    const float* __restrict__ gh, const float* __restrict__ bh,
    float* __restrict__ fg, float* __restrict__ hl) {
  __shared__ float lds_a[2][64 * 64];  // 2 x 16 KB

  const int tid = threadIdx.x;
  const int lane = tid & 63;
  const int wv = tid >> 6;  // 0..1
  const int cq = lane & 15;
  const int kg = lane >> 4;
  const int brow0 = blockIdx.x * 64;

  f32x4 acc[2][8];
#pragma unroll
  for (int rt = 0; rt < 2; ++rt)
#pragma unroll
    for (int ct = 0; ct < 8; ++ct) acc[rt][ct] = (f32x4){0.f, 0.f, 0.f, 0.f};

  int s_row[8], s_chk[8];
#pragma unroll
  for (int i = 0; i < 8; ++i) {
    int lin = (wv * 8 + i) * 64 + lane;
    s_row[i] = lin >> 4;
    s_chk[i] = (lin & 15) ^ ((lin >> 4) & 15);
  }

  auto stage = [&](int bufp, int ks) {
#pragma unroll
    for (int i = 0; i < 8; ++i) {
      const float* src =
          &x[(size_t)(brow0 + s_row[i]) * CC + ks * 64 + s_chk[i] * 4];
      gload_lds16(src, &lds_a[bufp][(wv * 8 + i) * 256]);
    }
  };

  stage(0, 0);
  __syncthreads();  // vmcnt(0) drain: buf0 visible

  for (int ks = 0; ks < 8; ++ks) {
    const int bufp = ks & 1;
    if (ks < 7) stage(bufp ^ 1, ks + 1);  // issue-early: fly during compute

    const int kb0 = ks * 64;
#pragma unroll
    for (int kh = 0; kh < 2; ++kh) {
      const int kb2 = kh * 32;
      bf16x8 bfr[8];
#pragma unroll
      for (int ct = 0; ct < 8; ++ct)
        bfr[ct] =
            *(const bf16x8*)&WcT[(ct * 16 + cq) * 512 + kb0 + kb2 + kg * 8];
      union {
        bf16x8 v;
        unsigned int u[4];
      } af[2];
#pragma unroll
      for (int rt = 0; rt < 2; ++rt) {
        const int rl = wv * 32 + rt * 16 + cq;  // local row; rl&15 == cq
        const int c0 = (kh * 8 + kg * 2) ^ cq;
        const int c1 = (kh * 8 + kg * 2 + 1) ^ cq;
        f32x4 a0 = *(const f32x4*)&lds_a[bufp][rl * 64 + c0 * 4];
        f32x4 a1 = *(const f32x4*)&lds_a[bufp][rl * 64 + c1 * 4];
        af[rt].u[0] = cvt_pk_bf16(a0[0], a0[1]);
        af[rt].u[1] = cvt_pk_bf16(a0[2], a0[3]);
        af[rt].u[2] = cvt_pk_bf16(a1[0], a1[1]);
        af[rt].u[3] = cvt_pk_bf16(a1[2], a1[3]);
      }
#pragma unroll
      for (int rt = 0; rt < 2; ++rt)
#pragma unroll
        for (int ct = 0; ct < 8; ++ct)
          acc[rt][ct] = __builtin_amdgcn_mfma_f32_16x16x32_bf16(
              af[rt].v, bfr[ct], acc[rt][ct], 0, 0, 0);
    }
    __syncthreads();  // drain next-tile loads + guard buffer reuse
  }

  // ---------------- LN epilogue ----------------
  float gfv[4], bfv[4], ghv[4], bhv[4];
#pragma unroll
  for (int ct = 0; ct < 4; ++ct) {
    gfv[ct] = gf[ct * 16 + cq];
    bfv[ct] = bf[ct * 16 + cq];
    ghv[ct] = gh[ct * 16 + cq];
    bhv[ct] = bh[ct * 16 + cq];
  }

#pragma unroll
  for (int rt = 0; rt < 2; ++rt) {
#pragma unroll
    for (int r = 0; r < 4; ++r) {
      const int row = brow0 + wv * 32 + rt * 16 + kg * 4 + r;
      float s = acc[rt][0][r] + acc[rt][1][r] + acc[rt][2][r] + acc[rt][3][r];
      float q = acc[rt][0][r] * acc[rt][0][r] + acc[rt][1][r] * acc[rt][1][r] +
                acc[rt][2][r] * acc[rt][2][r] + acc[rt][3][r] * acc[rt][3][r];
#pragma unroll
      for (int m = 1; m < 16; m <<= 1) {
        s += __shfl_xor(s, m, 64);
        q += __shfl_xor(q, m, 64);
      }
      float mean = s * (1.f / 64.f);
      float var = q * (1.f / 64.f) - mean * mean;
      float inv = rsqrtf(var + LN_EPS);
#pragma unroll
      for (int ct = 0; ct < 4; ++ct) {
        float v = (acc[rt][ct][r] - mean) * inv * gfv[ct] + bfv[ct];
        fg[(size_t)row * CI + ct * 16 + cq] = v;
      }
      float s2 = acc[rt][4][r] + acc[rt][5][r] + acc[rt][6][r] + acc[rt][7][r];
      float q2 = acc[rt][4][r] * acc[rt][4][r] + acc[rt][5][r] * acc[rt][5][r] +
                 acc[rt][6][r] * acc[rt][6][r] + acc[rt][7][r] * acc[rt][7][r];
#pragma unroll
      for (int m = 1; m < 16; m <<= 1) {
        s2 += __shfl_xor(s2, m, 64);
        q2 += __shfl_xor(q2, m, 64);
      }
      float mean2 = s2 * (1.f / 64.f);
      float var2 = q2 * (1.f / 64.f) - mean2 * mean2;
      float inv2 = rsqrtf(var2 + LN_EPS);
#pragma unroll
      for (int ct = 0; ct < 4; ++ct) {
        float v = (acc[rt][ct + 4][r] - mean2) * inv2 * ghv[ct] + bhv[ct];
        hl[(size_t)row * CI + ct * 16 + cq] = v;
      }
    }
  }
}

// ---------------------------------------------------------------------------
// K23 fused, 256 threads (4 waves), waves_per_eu(4,4): exact 4 waves/EU bin
// (<=128 VGPR, no incentive to over-shrink -> avoids R13's 64-VGPR spill).
// Satisfiable because phase B is now FOUR 16-row passes (acc[8]=32 regs live,
// ah/al 8, bfr 16 -> ~100 peak) and phase A keeps no per-thread arrays
// (prod[] LDS scratch). Target: 16 waves/CU, 2x all prior K23 variants.
// Math identical to R15 (same per-row stat grouping, same rounding).
// ---------------------------------------------------------------------------
__global__ __attribute__((amdgpu_waves_per_eu(4, 4))) __launch_bounds__(256)
void sgsa_k23(
    const float* __restrict__ fg, const float* __restrict__ hl,
    const unsigned short* __restrict__ WoT, const float* __restrict__ go,
    const float* __restrict__ bo, const float* __restrict__ scale,
    const float* __restrict__ x, float* __restrict__ out) {
  // Bijective XCD swizzle: nwg=1024, 8 XCDs, 128 contiguous blocks per XCD.
  const int bid = (int)(blockIdx.x & 7) * 128 + (int)(blockIdx.x >> 3);
  const int b = bid >> 6;
  const int w = bid & 63;
  const int tid = threadIdx.x;
  const int lane = tid & 63;
  const int wv = tid >> 6;  // 0..3

  __shared__ unsigned short t_hi[64 * 72];  // 9 KB
  __shared__ unsigned short t_lo[64 * 72];  // 9 KB
  __shared__ float prod[64 * 68];           // 17.4 KB  exp(s)*hv scratch
  __shared__ float red[4][64];              // 1 KB
  __shared__ float s_red[4][16];
  __shared__ float q_red[4][16];

  const size_t base_g = ((size_t)(b * 64) * 64 + w) * 64;  // + h*4096 + d
  const size_t base_f = ((size_t)(b * 64 + w) * 64) * 64;  // + h*64 + d

  // ---------------- Phase A: softmax over h (no max-sub), t in LDS --------
  {
    const int d = lane;
    const int q = wv;  // each (q,d) owns 16 h values
    float ssum = 0.f;
#pragma unroll
    for (int i = 0; i < 16; ++i) {
      int h = q * 16 + i;
      float g = fg[base_g + (size_t)h * 4096 + d];
      float f = fg[base_f + (size_t)h * 64 + d];
      float hv = hl[base_g + (size_t)h * 4096 + d];
      float e = __expf(f * g);
      ssum += e;
      prod[h * 68 + d] = e * hv;
    }
    red[q][d] = ssum;
    __syncthreads();
    ssum = (red[0][d] + red[1][d]) + (red[2][d] + red[3][d]);
    float rinv = 1.f / ssum;

#pragma unroll
    for (int i = 0; i < 16; ++i) {
      int h = q * 16 + i;
      float t = prod[h * 68 + d] * rinv;
      unsigned short th = f2bf(t);
      t_hi[h * 72 + d] = th;
      t_lo[h * 72 + d] = f2bf(t - bf2f(th));
    }
  }
  __syncthreads();

  // ---------------- Phase B: t @ Wo, LN over C, residual (4 row-passes) ----
  const int col0 = wv * 128;
  const int cq = lane & 15;
  const int kg = lane >> 4;
  const float sc = scale[0];

#pragma unroll 1
  for (int pass = 0; pass < 4; ++pass) {
    const int trow0 = pass * 16;

    f32x4 acc[8];
#pragma unroll
    for (int ct = 0; ct < 8; ++ct) acc[ct] = (f32x4){0.f, 0.f, 0.f, 0.f};

#pragma unroll
    for (int kk = 0; kk < 2; ++kk) {
      const int kb = kk * 32 + kg * 8;
      bf16x8 ah = *(const bf16x8*)&t_hi[(trow0 + cq) * 72 + kb];
      bf16x8 al = *(const bf16x8*)&t_lo[(trow0 + cq) * 72 + kb];
#pragma unroll
      for (int half = 0; half < 2; ++half) {
        bf16x8 bfr[4];
#pragma unroll
        for (int c4 = 0; c4 < 4; ++c4) {
          const int ct = half * 4 + c4;
          bfr[c4] = *(const bf16x8*)&WoT[(col0 + ct * 16 + cq) * CI + kb];
        }
#pragma unroll
        for (int c4 = 0; c4 < 4; ++c4) {
          const int ct = half * 4 + c4;
          acc[ct] = __builtin_amdgcn_mfma_f32_16x16x32_bf16(ah, bfr[c4],
                                                            acc[ct], 0, 0, 0);
          acc[ct] = __builtin_amdgcn_mfma_f32_16x16x32_bf16(al, bfr[c4],
                                                            acc[ct], 0, 0, 0);
        }
      }
    }

    // per-row partial LN stats over this wave's 128 cols -> LDS
#pragma unroll
    for (int r = 0; r < 4; ++r) {
      float s = 0.f, qq = 0.f;
#pragma unroll
      for (int ct = 0; ct < 8; ++ct) {
        float v = acc[ct][r];
        s += v;
        qq += v * v;
      }
#pragma unroll
      for (int m = 1; m < 16; m <<= 1) {
        s += __shfl_xor(s, m, 64);
        qq += __shfl_xor(qq, m, 64);
      }
      if (cq == 0) {
        s_red[wv][kg * 4 + r] = s;
        q_red[wv][kg * 4 + r] = qq;
      }
    }
    __syncthreads();  // stats visible

#pragma unroll
    for (int r = 0; r < 4; ++r) {
      const int rl = kg * 4 + r;  // row within 16-row pass
      const int h = trow0 + rl;
      float s = (s_red[0][rl] + s_red[1][rl]) + (s_red[2][rl] + s_red[3][rl]);
      float q = (q_red[0][rl] + q_red[1][rl]) + (q_red[2][rl] + q_red[3][rl]);
      float mean = s * (1.f / 512.f);
      float var = q * (1.f / 512.f) - mean * mean;
      float inv = rsqrtf(var + LN_EPS);
      const size_t base = (size_t)((b * 64 + h) * 64 + w) * CC;
#pragma unroll
      for (int ct = 0; ct < 8; ++ct) {
        const int col = col0 + ct * 16 + cq;
        float o = (acc[ct][r] - mean) * inv * go[col] + bo[col];
        out[base + col] = o * sc + x[base + col];
      }
    }
    if (pass < 3) __syncthreads();  // guard s_red reuse by next pass
  }
}

// ---------------------------------------------------------------------------
extern "C" void kernel_launch(void* const* d_in, const int* in_sizes, int n_in,
                              void* d_out, int out_size, void* d_ws,
                              size_t ws_size, hipStream_t stream) {
  const float* x = (const float*)d_in[0];
  const float* Wf = (const float*)d_in[1];
  const float* Wh = (const float*)d_in[2];
  const float* Wo = (const float*)d_in[3];
  const float* gf = (const float*)d_in[4];
  const float* bf = (const float*)d_in[5];
  const float* gh = (const float*)d_in[6];
  const float* bh = (const float*)d_in[7];
  const float* go = (const float*)d_in[8];
  const float* bo = (const float*)d_in[9];
  const float* sc = (const float*)d_in[10];
  float* out = (float*)d_out;

  unsigned short* WcT = (unsigned short*)d_ws;      // 128*512*2 = 128 KiB
  unsigned short* WoT = WcT + 128 * 512;            // 512*64*2  =  64 KiB
  float* fg = (float*)((char*)d_ws + (256 << 10));  // 16 MiB
  float* hl = fg + (size_t)NROWS * CI;              // 16 MiB

  sgsa_prep<<<128, 256, 0, stream>>>(Wf, Wh, Wo, WcT, WoT);
  sgsa_k1_mfma<<<NROWS / 64, 128, 0, stream>>>(x, WcT, gf, bf, gh, bh, fg, hl);
  sgsa_k23<<<BB * WW, 256, 0, stream>>>(fg, hl, WoT, go, bo, sc, x, out);
}

// Round 17
// 116.559 us; speedup vs baseline: 1.3089x; 1.3089x over previous
//
#include <hip/hip_runtime.h>
#include <math.h>

// Problem dims (fixed by setup_inputs)
#define BB 16
#define HH 64
#define WW 64
#define CC 512
#define CI 64
#define NROWS (BB * HH * WW)  // 65536 rows of length C
#define LN_EPS 1e-3f

typedef __attribute__((ext_vector_type(8))) short bf16x8;
typedef __attribute__((ext_vector_type(4))) float f32x4;

__device__ __forceinline__ unsigned short f2bf(float f) {
  union {
    float f;
    unsigned int u;
  } v;
  v.f = f;
  unsigned int r = v.u + 0x7FFF + ((v.u >> 16) & 1);  // RNE
  return (unsigned short)(r >> 16);
}

__device__ __forceinline__ float bf2f(unsigned short u) {
  union {
    unsigned int u;
    float f;
  } v;
  v.u = ((unsigned int)u) << 16;
  return v.f;
}

// Packed f32->bf16 (RNE) — register-only asm, deps tracked via operands.
__device__ __forceinline__ unsigned int cvt_pk_bf16(float a, float b) {
  unsigned int r;
  asm("v_cvt_pk_bf16_f32 %0, %1, %2" : "=v"(r) : "v"(a), "v"(b));
  return r;  // low16 = bf(a), high16 = bf(b)
}

// Async global->LDS, 16B per lane. LDS dest is wave-uniform base + lane*16;
// the GLOBAL source address is per-lane.
__device__ __forceinline__ void gload_lds16(const float* g, float* l) {
  __builtin_amdgcn_global_load_lds(
      (const __attribute__((address_space(1))) void*)g,
      (__attribute__((address_space(3))) void*)l, 16, 0, 0);
}

// ---------------------------------------------------------------------------
// Prep: transpose weights to k-contiguous bf16. WcT[col][k]: col<64 -> Wf,
// col in [64,128) -> Wh. WoT[col][k] from Wo[k][col].
// ---------------------------------------------------------------------------
__global__ __launch_bounds__(256) void sgsa_prep(
    const float* __restrict__ Wf, const float* __restrict__ Wh,
    const float* __restrict__ Wo, unsigned short* __restrict__ WcT,
    unsigned short* __restrict__ WoT) {
  int tid = blockIdx.x * 256 + threadIdx.x;
  for (int i = tid; i < 128 * 512; i += gridDim.x * 256) {
    int col = i >> 9, k = i & 511;
    float v = (col < 64) ? Wf[k * 64 + col] : Wh[k * 64 + (col - 64)];
    WcT[i] = f2bf(v);
  }
  for (int i = tid; i < 512 * 64; i += gridDim.x * 256) {
    int col = i >> 6, k = i & 63;
    WoT[i] = f2bf(Wo[k * 512 + col]);
  }
}

// ---------------------------------------------------------------------------
// K1 (double-buffered staged MFMA): [fg|hl] = LN( x @ [Wf|Wh] ).
// M=65536, N=128, K=512. Block = 128 rows, 4 waves; wave = 32 rows x 128 cols.
// BK=32: two 16 KB LDS buffers; STAGE(next K-step) issued BEFORE compute of
// the current step, ONE vmcnt(0)+barrier per step (T3-min 2-phase template)
// so next-step HBM loads fly during current-step ds_read/cvt/MFMA.
// LDS rows of 8 chunks (16B); physical chunk p of row holds logical p^(row&7)
// (swizzle applied to the GLOBAL source; gload_lds dest stays linear).
// D layout (m89-verified): col = lane&15, row = (lane>>4)*4 + reg.
// ---------------------------------------------------------------------------
__global__ __launch_bounds__(256) void sgsa_k1_mfma(
    const float* __restrict__ x, const unsigned short* __restrict__ WcT,
    const float* __restrict__ gf, const float* __restrict__ bf,
    const float* __restrict__ gh, const float* __restrict__ bh,
    float* __restrict__ fg, float* __restrict__ hl) {
  __shared__ float lds_a[2][128 * 32];  // 2 x 16 KB

  const int tid = threadIdx.x;
  const int lane = tid & 63;
  const int wv = tid >> 6;
  const int cq = lane & 15;  // A-row-in-tile / B-col-in-tile / D-col
  const int kg = lane >> 4;  // k-group
  const int brow0 = blockIdx.x * 128;

  f32x4 acc[2][8];
#pragma unroll
  for (int rt = 0; rt < 2; ++rt)
#pragma unroll
    for (int ct = 0; ct < 8; ++ct) acc[rt][ct] = (f32x4){0.f, 0.f, 0.f, 0.f};

  // Per-wave staging map: 4 issues cover chunks lin=(wv*4+i)*64+lane
  // (1024 chunks = 128 rows x 8 chunks). row=lin>>3, physical cp=lin&7,
  // logical (global) chunk = cp ^ (row&7).
  int s_row[4], s_chk[4];
#pragma unroll
  for (int i = 0; i < 4; ++i) {
    int lin = (wv * 4 + i) * 64 + lane;
    s_row[i] = lin >> 3;
    s_chk[i] = (lin & 7) ^ ((lin >> 3) & 7);
  }

  auto stage = [&](int bufp, int ks) {
#pragma unroll
    for (int i = 0; i < 4; ++i) {
      const float* src =
          &x[(size_t)(brow0 + s_row[i]) * CC + ks * 32 + s_chk[i] * 4];
      gload_lds16(src, &lds_a[bufp][(wv * 4 + i) * 256]);
    }
  };

  stage(0, 0);
  __syncthreads();  // vmcnt(0) drain: buf0 visible

  for (int ks = 0; ks < 16; ++ks) {
    const int bufp = ks & 1;
    if (ks < 15) stage(bufp ^ 1, ks + 1);  // issue-early: fly during compute

    const int kb0 = ks * 32;
    bf16x8 bfr[8];
#pragma unroll
    for (int ct = 0; ct < 8; ++ct)
      bfr[ct] = *(const bf16x8*)&WcT[(ct * 16 + cq) * 512 + kb0 + kg * 8];

    union {
      bf16x8 v;
      unsigned int u[4];
    } af[2];
#pragma unroll
    for (int rt = 0; rt < 2; ++rt) {
      const int rl = wv * 32 + rt * 16 + cq;
      const int c0 = (kg * 2) ^ (rl & 7);
      const int c1 = (kg * 2 + 1) ^ (rl & 7);
      f32x4 a0 = *(const f32x4*)&lds_a[bufp][rl * 32 + c0 * 4];
      f32x4 a1 = *(const f32x4*)&lds_a[bufp][rl * 32 + c1 * 4];
      af[rt].u[0] = cvt_pk_bf16(a0[0], a0[1]);
      af[rt].u[1] = cvt_pk_bf16(a0[2], a0[3]);
      af[rt].u[2] = cvt_pk_bf16(a1[0], a1[1]);
      af[rt].u[3] = cvt_pk_bf16(a1[2], a1[3]);
    }
#pragma unroll
    for (int rt = 0; rt < 2; ++rt)
#pragma unroll
      for (int ct = 0; ct < 8; ++ct)
        acc[rt][ct] = __builtin_amdgcn_mfma_f32_16x16x32_bf16(
            af[rt].v, bfr[ct], acc[rt][ct], 0, 0, 0);

    __syncthreads();  // drain next-tile loads + guard buffer reuse
  }

  // ---------------- LN epilogue ----------------
  float gfv[4], bfv[4], ghv[4], bhv[4];
#pragma unroll
  for (int ct = 0; ct < 4; ++ct) {
    gfv[ct] = gf[ct * 16 + cq];
    bfv[ct] = bf[ct * 16 + cq];
    ghv[ct] = gh[ct * 16 + cq];
    bhv[ct] = bh[ct * 16 + cq];
  }

#pragma unroll
  for (int rt = 0; rt < 2; ++rt) {
#pragma unroll
    for (int r = 0; r < 4; ++r) {
      const int row = brow0 + wv * 32 + rt * 16 + kg * 4 + r;
      float s = acc[rt][0][r] + acc[rt][1][r] + acc[rt][2][r] + acc[rt][3][r];
      float q = acc[rt][0][r] * acc[rt][0][r] + acc[rt][1][r] * acc[rt][1][r] +
                acc[rt][2][r] * acc[rt][2][r] + acc[rt][3][r] * acc[rt][3][r];
#pragma unroll
      for (int m = 1; m < 16; m <<= 1) {
        s += __shfl_xor(s, m, 64);
        q += __shfl_xor(q, m, 64);
      }
      float mean = s * (1.f / 64.f);
      float var = q * (1.f / 64.f) - mean * mean;
      float inv = rsqrtf(var + LN_EPS);
#pragma unroll
      for (int ct = 0; ct < 4; ++ct) {
        float v = (acc[rt][ct][r] - mean) * inv * gfv[ct] + bfv[ct];
        fg[(size_t)row * CI + ct * 16 + cq] = v;
      }
      float s2 = acc[rt][4][r] + acc[rt][5][r] + acc[rt][6][r] + acc[rt][7][r];
      float q2 = acc[rt][4][r] * acc[rt][4][r] + acc[rt][5][r] * acc[rt][5][r] +
                 acc[rt][6][r] * acc[rt][6][r] + acc[rt][7][r] * acc[rt][7][r];
#pragma unroll
      for (int m = 1; m < 16; m <<= 1) {
        s2 += __shfl_xor(s2, m, 64);
        q2 += __shfl_xor(q2, m, 64);
      }
      float mean2 = s2 * (1.f / 64.f);
      float var2 = q2 * (1.f / 64.f) - mean2 * mean2;
      float inv2 = rsqrtf(var2 + LN_EPS);
#pragma unroll
      for (int ct = 0; ct < 4; ++ct) {
        float v = (acc[rt][ct + 4][r] - mean2) * inv2 * ghv[ct] + bhv[ct];
        hl[(size_t)row * CI + ct * 16 + cq] = v;
      }
    }
  }
}

// ---------------------------------------------------------------------------
// K23 fused, 512 threads (8 waves), (512,2) — the R9 best-measured version.
// Phase A inputs (f contiguous; g, hl strided) staged via gload_lds
// fire-and-forget (48 KB in flight in one burst), softmax reads from LDS.
// Phase B: wave wv -> (row-half, col-quarter), split-bf16 t from LDS,
// cross-wave LN, xv residual hoist before the final barrier.
// ---------------------------------------------------------------------------
__global__ __launch_bounds__(512, 2) void sgsa_k23(
    const float* __restrict__ fg, const float* __restrict__ hl,
    const unsigned short* __restrict__ WoT, const float* __restrict__ go,
    const float* __restrict__ bo, const float* __restrict__ scale,
    const float* __restrict__ x, float* __restrict__ out) {
  const int b = blockIdx.x >> 6;
  const int w = blockIdx.x & 63;
  const int tid = threadIdx.x;
  const int lane = tid & 63;
  const int wv = tid >> 6;

  __shared__ float lds_f[64 * 64];  // 16 KB  f[h][d]
  __shared__ float lds_g[64 * 64];  // 16 KB  g[h][d]
  __shared__ float lds_h[64 * 64];  // 16 KB  hl[h][d]
  __shared__ unsigned short t_hi[64 * 72];
  __shared__ unsigned short t_lo[64 * 72];
  __shared__ float redA[8][64];
  __shared__ float redB[8][64];
  __shared__ float s_red[8][32];
  __shared__ float q_red[8][32];

  const size_t base_g = ((size_t)(b * 64) * 64 + w) * 64;  // + h*4096 + d
  const size_t base_f = ((size_t)(b * 64 + w) * 64) * 64;  // + h*64 + d

  // ---- Stage phase-A inputs (fire-and-forget, per-lane global addresses,
  // linear LDS dests). 1024 chunks of 16B per region; 2 issues/wave each.
#pragma unroll
  for (int i = 0; i < 2; ++i) {
    const int c = (wv * 2 + i) * 64 + lane;  // chunk id 0..1023
    const int grp = (wv * 2 + i) * 256;      // issue-group float offset
    gload_lds16(&fg[base_f + (size_t)c * 4], &lds_f[grp]);
    const size_t soff = (size_t)(c >> 4) * 4096 + (c & 15) * 4;
    gload_lds16(&fg[base_g + soff], &lds_g[grp]);
    gload_lds16(&hl[base_g + soff], &lds_h[grp]);
  }
  __syncthreads();  // vmcnt(0): staged data visible

  // ---------------- Phase A: softmax over h, build t in LDS ----------------
  {
    const int d = tid & 63;
    const int q = tid >> 6;  // 0..7, each owns 8 h values
    float sv[8];
    float m = -1e30f;
#pragma unroll
    for (int i = 0; i < 8; ++i) {
      int h = q * 8 + i;
      sv[i] = lds_f[h * 64 + d] * lds_g[h * 64 + d];
      m = fmaxf(m, sv[i]);
    }
    redA[q][d] = m;
    __syncthreads();
#pragma unroll
    for (int j = 0; j < 8; ++j) m = fmaxf(m, redA[j][d]);

    float ssum = 0.f;
#pragma unroll
    for (int i = 0; i < 8; ++i) {
      sv[i] = __expf(sv[i] - m);
      ssum += sv[i];
    }
    redB[q][d] = ssum;
    __syncthreads();
    ssum = 0.f;
#pragma unroll
    for (int j = 0; j < 8; ++j) ssum += redB[j][d];
    float rinv = 1.f / ssum;

#pragma unroll
    for (int i = 0; i < 8; ++i) {
      int h = q * 8 + i;
      float t = sv[i] * rinv * lds_h[h * 64 + d];
      unsigned short th = f2bf(t);
      t_hi[h * 72 + d] = th;
      t_lo[h * 72 + d] = f2bf(t - bf2f(th));
    }
  }
  __syncthreads();

  // ---------------- Phase B: t @ Wo, LN over C, residual -------------------
  const int rh = wv >> 2;  // row half: rows rh*32 .. rh*32+31
  const int cw = wv & 3;   // col quarter
  const int col0 = cw * 128;
  const int cq = lane & 15;
  const int kg = lane >> 4;
  const int trow0 = rh * 32;

  f32x4 acc[2][8];
#pragma unroll
  for (int rt = 0; rt < 2; ++rt)
#pragma unroll
    for (int ct = 0; ct < 8; ++ct) acc[rt][ct] = (f32x4){0.f, 0.f, 0.f, 0.f};

#pragma unroll
  for (int kk = 0; kk < 2; ++kk) {
    const int kb = kk * 32 + kg * 8;
    bf16x8 ah[2], al[2];
#pragma unroll
    for (int rt = 0; rt < 2; ++rt) {
      ah[rt] = *(const bf16x8*)&t_hi[(trow0 + rt * 16 + cq) * 72 + kb];
      al[rt] = *(const bf16x8*)&t_lo[(trow0 + rt * 16 + cq) * 72 + kb];
    }
#pragma unroll
    for (int half = 0; half < 2; ++half) {
      bf16x8 bfr[4];
#pragma unroll
      for (int c4 = 0; c4 < 4; ++c4) {
        const int ct = half * 4 + c4;
        bfr[c4] = *(const bf16x8*)&WoT[(col0 + ct * 16 + cq) * CI + kb];
      }
#pragma unroll
      for (int rt = 0; rt < 2; ++rt) {
#pragma unroll
        for (int c4 = 0; c4 < 4; ++c4) {
          const int ct = half * 4 + c4;
          acc[rt][ct] = __builtin_amdgcn_mfma_f32_16x16x32_bf16(
              ah[rt], bfr[c4], acc[rt][ct], 0, 0, 0);
          acc[rt][ct] = __builtin_amdgcn_mfma_f32_16x16x32_bf16(
              al[rt], bfr[c4], acc[rt][ct], 0, 0, 0);
        }
      }
    }
  }

  // per-row partial LN stats over this wave's 128 cols -> LDS
#pragma unroll
  for (int rt = 0; rt < 2; ++rt) {
#pragma unroll
    for (int r = 0; r < 4; ++r) {
      float s = 0.f, qq = 0.f;
#pragma unroll
      for (int ct = 0; ct < 8; ++ct) {
        float v = acc[rt][ct][r];
        s += v;
        qq += v * v;
      }
#pragma unroll
      for (int m = 1; m < 16; m <<= 1) {
        s += __shfl_xor(s, m, 64);
        qq += __shfl_xor(qq, m, 64);
      }
      if (cq == 0) {
        s_red[wv][rt * 16 + kg * 4 + r] = s;
        q_red[wv][rt * 16 + kg * 4 + r] = qq;
      }
    }
  }

  // x residual loads in flight while waiting on the reduce barrier.
  float xv[2][4][8];
#pragma unroll
  for (int rt = 0; rt < 2; ++rt) {
#pragma unroll
    for (int r = 0; r < 4; ++r) {
      const int h = trow0 + rt * 16 + kg * 4 + r;
      const size_t base = (size_t)((b * 64 + h) * 64 + w) * CC;
#pragma unroll
      for (int ct = 0; ct < 8; ++ct)
        xv[rt][r][ct] = x[base + col0 + ct * 16 + cq];
    }
  }
  __syncthreads();

  const float sc = scale[0];
  float gov[8], bov[8];
#pragma unroll
  for (int ct = 0; ct < 8; ++ct) {
    gov[ct] = go[col0 + ct * 16 + cq];
    bov[ct] = bo[col0 + ct * 16 + cq];
  }

#pragma unroll
  for (int rt = 0; rt < 2; ++rt) {
#pragma unroll
    for (int r = 0; r < 4; ++r) {
      const int rl = rt * 16 + kg * 4 + r;  // row within half-tile
      const int h = trow0 + rl;
      float s = (s_red[rh * 4 + 0][rl] + s_red[rh * 4 + 1][rl]) +
                (s_red[rh * 4 + 2][rl] + s_red[rh * 4 + 3][rl]);
      float q = (q_red[rh * 4 + 0][rl] + q_red[rh * 4 + 1][rl]) +
                (q_red[rh * 4 + 2][rl] + q_red[rh * 4 + 3][rl]);
      float mean = s * (1.f / 512.f);
      float var = q * (1.f / 512.f) - mean * mean;
      float inv = rsqrtf(var + LN_EPS);
      const size_t base = (size_t)((b * 64 + h) * 64 + w) * CC;
#pragma unroll
      for (int ct = 0; ct < 8; ++ct) {
        const int col = col0 + ct * 16 + cq;
        float o = (acc[rt][ct][r] - mean) * inv * gov[ct] + bov[ct];
        out[base + col] = o * sc + xv[rt][r][ct];
      }
    }
  }
}

// ---------------------------------------------------------------------------
extern "C" void kernel_launch(void* const* d_in, const int* in_sizes, int n_in,
                              void* d_out, int out_size, void* d_ws,
                              size_t ws_size, hipStream_t stream) {
  const float* x = (const float*)d_in[0];
  const float* Wf = (const float*)d_in[1];
  const float* Wh = (const float*)d_in[2];
  const float* Wo = (const float*)d_in[3];
  const float* gf = (const float*)d_in[4];
  const float* bf = (const float*)d_in[5];
  const float* gh = (const float*)d_in[6];
  const float* bh = (const float*)d_in[7];
  const float* go = (const float*)d_in[8];
  const float* bo = (const float*)d_in[9];
  const float* sc = (const float*)d_in[10];
  float* out = (float*)d_out;

  unsigned short* WcT = (unsigned short*)d_ws;      // 128*512*2 = 128 KiB
  unsigned short* WoT = WcT + 128 * 512;            // 512*64*2  =  64 KiB
  float* fg = (float*)((char*)d_ws + (256 << 10));  // 16 MiB
  float* hl = fg + (size_t)NROWS * CI;              // 16 MiB

  sgsa_prep<<<128, 256, 0, stream>>>(Wf, Wh, Wo, WcT, WoT);
  sgsa_k1_mfma<<<NROWS / 128, 256, 0, stream>>>(x, WcT, gf, bf, gh, bh, fg,
                                                hl);
  sgsa_k23<<<BB * WW, 512, 0, stream>>>(fg, hl, WoT, go, bo, sc, x, out);
}